// Round 2
// baseline (2305.321 us; speedup 1.0000x reference)
//
#include <hip/hip_runtime.h>

// Graph-transformer MHA layer. N=50000, E=1600000, IN_DIM=64, H=8, D=8.
// Outputs: h_out [N*64] then e_out [E*64], fp32, concatenated in d_out.
//
// R2 structure (no per-dim scatter atomics):
//  1) memset counts
//  2) proj_kernel: Q,K,V = h@W+b
//  3) hist_kernel: counts[dst]++
//  4) scan_kernel: offsets = exscan(counts); cursor = offsets
//  5) edge_kernel: pe = e@We+be; score = K[src]*Q[dst]*pe/sqrt(D); e_out = score;
//     s = exp(clip(sum_head score)); pos = cursor[dst]++ (1 atomic/edge);
//     s_sorted[pos][8] = s; src_sorted[pos] = src
//  6) aggregate_kernel: one wave per node, streams its sorted segment,
//     gathers V[src], writes h_out = sum(s*V)/(sum(s)+1e-6). No atomics.

// ---------------- node projection ----------------
__global__ __launch_bounds__(256)
void proj_kernel(const float* __restrict__ hsrc,
                 const float* __restrict__ Wq, const float* __restrict__ bq,
                 const float* __restrict__ Wk, const float* __restrict__ bk,
                 const float* __restrict__ Wv, const float* __restrict__ bv,
                 float* __restrict__ Q, float* __restrict__ K, float* __restrict__ V,
                 int n)
{
    const float* W;
    const float* b;
    float* out;
    if (blockIdx.y == 0)      { W = Wq; b = bq; out = Q; }
    else if (blockIdx.y == 1) { W = Wk; b = bk; out = K; }
    else                      { W = Wv; b = bv; out = V; }

    const int t    = threadIdx.x;
    const int lane = t & 63;
    const int w    = t >> 6;

    float wcol[64];
#pragma unroll
    for (int k = 0; k < 64; ++k) wcol[k] = W[k * 64 + lane];
    const float bias = b[lane];

    __shared__ float4 sh[16][16];
    const float4* __restrict__ h4 = (const float4*)hsrc;

    const int ngroups = (n + 15) >> 4;
    for (int g = blockIdx.x; g < ngroups; g += gridDim.x) {
        const int base = g << 4;
        {
            const int rs = t >> 4, c4 = t & 15;
            float4 v = make_float4(0.f, 0.f, 0.f, 0.f);
            if (base + rs < n) v = h4[(size_t)(base + rs) * 16 + c4];
            __syncthreads();
            sh[rs][c4] = v;
            __syncthreads();
        }
        float acc0 = bias, acc1 = bias, acc2 = bias, acc3 = bias;
#pragma unroll
        for (int k4 = 0; k4 < 16; ++k4) {
            const float w0 = wcol[k4 * 4 + 0], w1 = wcol[k4 * 4 + 1];
            const float w2 = wcol[k4 * 4 + 2], w3 = wcol[k4 * 4 + 3];
            const float4 a = sh[w * 4 + 0][k4];
            const float4 bb = sh[w * 4 + 1][k4];
            const float4 c = sh[w * 4 + 2][k4];
            const float4 d = sh[w * 4 + 3][k4];
            acc0 = fmaf(a.w,  w3, fmaf(a.z,  w2, fmaf(a.y,  w1, fmaf(a.x,  w0, acc0))));
            acc1 = fmaf(bb.w, w3, fmaf(bb.z, w2, fmaf(bb.y, w1, fmaf(bb.x, w0, acc1))));
            acc2 = fmaf(c.w,  w3, fmaf(c.z,  w2, fmaf(c.y,  w1, fmaf(c.x,  w0, acc2))));
            acc3 = fmaf(d.w,  w3, fmaf(d.z,  w2, fmaf(d.y,  w1, fmaf(d.x,  w0, acc3))));
        }
        const int n0 = base + w * 4;
        if (n0 + 0 < n) out[(size_t)(n0 + 0) * 64 + lane] = acc0;
        if (n0 + 1 < n) out[(size_t)(n0 + 1) * 64 + lane] = acc1;
        if (n0 + 2 < n) out[(size_t)(n0 + 2) * 64 + lane] = acc2;
        if (n0 + 3 < n) out[(size_t)(n0 + 3) * 64 + lane] = acc3;
    }
}

// ---------------- dst histogram ----------------
__global__ __launch_bounds__(256)
void hist_kernel(const int* __restrict__ dst, int* __restrict__ counts, int E)
{
    int i = blockIdx.x * 256 + threadIdx.x;
    const int stride = gridDim.x * 256;
    for (; i < E; i += stride) atomicAdd(&counts[dst[i]], 1);
}

// ---------------- exclusive scan over counts (single block, 1024 thr) ----------------
__global__ __launch_bounds__(1024)
void scan_kernel(const int* __restrict__ counts, int* __restrict__ offsets,
                 int* __restrict__ cursor, int n, int E)
{
    __shared__ int wsum[16];
    const int t = threadIdx.x;
    const int lane = t & 63;
    const int w = t >> 6;
    int carry = 0;
    for (int base = 0; base < n; base += 1024) {
        const int i = base + t;
        const int v = (i < n) ? counts[i] : 0;
        int x = v;
#pragma unroll
        for (int d = 1; d < 64; d <<= 1) {
            int y = __shfl_up(x, d);
            if (lane >= d) x += y;
        }
        if (lane == 63) wsum[w] = x;
        __syncthreads();
        if (w == 0 && lane < 16) {
            int s = wsum[lane];
#pragma unroll
            for (int d = 1; d < 16; d <<= 1) {
                int y = __shfl_up(s, d);
                if (lane >= d) s += y;
            }
            wsum[lane] = s;
        }
        __syncthreads();
        const int woff = (w == 0) ? 0 : wsum[w - 1];
        const int excl = carry + woff + (x - v);
        if (i < n) { offsets[i] = excl; cursor[i] = excl; }
        carry += wsum[15];
        __syncthreads();
    }
    if (t == 0) offsets[n] = E;
}

// ---------------- edge kernel: projection + score + slot scatter ----------------
__global__ __launch_bounds__(256)
void edge_kernel(const float* __restrict__ e,
                 const float* __restrict__ We, const float* __restrict__ be,
                 const int* __restrict__ src, const int* __restrict__ dst,
                 const float* __restrict__ Q, const float* __restrict__ K,
                 float* __restrict__ e_out,
                 float* __restrict__ s_sorted, int* __restrict__ src_sorted,
                 int* __restrict__ cursor, int E)
{
    const int t    = threadIdx.x;
    const int lane = t & 63;
    const int w    = t >> 6;

    float wcol[64];
#pragma unroll
    for (int k = 0; k < 64; ++k) wcol[k] = We[k * 64 + lane];
    const float bias = be[lane];
    const float inv_sqrt_d = 0.35355339059327373f; // 1/sqrt(8)

    __shared__ float4 se[16][16];
    const float4* __restrict__ e4 = (const float4*)e;

    const int ngroups = (E + 15) >> 4;
    for (int g = blockIdx.x; g < ngroups; g += gridDim.x) {
        const int base = g << 4;
        {
            const int rs = t >> 4, c4 = t & 15;
            float4 v = make_float4(0.f, 0.f, 0.f, 0.f);
            if (base + rs < E) v = e4[(size_t)(base + rs) * 16 + c4];
            __syncthreads();
            se[rs][c4] = v;
            __syncthreads();
        }
        // indices + gathers for the wave's 4 edges, issued early for ILP
        int se_[4], de_[4];
#pragma unroll
        for (int m = 0; m < 4; ++m) {
            const int eid = base + w * 4 + m;
            se_[m] = (eid < E) ? src[eid] : 0;
            de_[m] = (eid < E) ? dst[eid] : 0;
        }
        float kv[4], qv[4];
#pragma unroll
        for (int m = 0; m < 4; ++m) {
            kv[m] = K[(size_t)se_[m] * 64 + lane];
            qv[m] = Q[(size_t)de_[m] * 64 + lane];
        }

        float acc[4];
        acc[0] = bias; acc[1] = bias; acc[2] = bias; acc[3] = bias;
#pragma unroll
        for (int k4 = 0; k4 < 16; ++k4) {
            const float w0 = wcol[k4 * 4 + 0], w1 = wcol[k4 * 4 + 1];
            const float w2 = wcol[k4 * 4 + 2], w3 = wcol[k4 * 4 + 3];
            const float4 a = se[w * 4 + 0][k4];
            const float4 bb = se[w * 4 + 1][k4];
            const float4 c = se[w * 4 + 2][k4];
            const float4 d = se[w * 4 + 3][k4];
            acc[0] = fmaf(a.w,  w3, fmaf(a.z,  w2, fmaf(a.y,  w1, fmaf(a.x,  w0, acc[0]))));
            acc[1] = fmaf(bb.w, w3, fmaf(bb.z, w2, fmaf(bb.y, w1, fmaf(bb.x, w0, acc[1]))));
            acc[2] = fmaf(c.w,  w3, fmaf(c.z,  w2, fmaf(c.y,  w1, fmaf(c.x,  w0, acc[2]))));
            acc[3] = fmaf(d.w,  w3, fmaf(d.z,  w2, fmaf(d.y,  w1, fmaf(d.x,  w0, acc[3]))));
        }
#pragma unroll
        for (int m = 0; m < 4; ++m) {
            const int eid = base + w * 4 + m;
            if (eid < E) {
                const float score = kv[m] * qv[m] * inv_sqrt_d * acc[m];
                e_out[(size_t)eid * 64 + lane] = score;
                float hs = score;
                hs += __shfl_xor(hs, 1);
                hs += __shfl_xor(hs, 2);
                hs += __shfl_xor(hs, 4);
                const float sg = expf(fminf(fmaxf(hs, -5.f), 5.f));
                int pos;
                if (lane == 0) pos = atomicAdd(&cursor[de_[m]], 1);
                pos = __shfl(pos, 0);
                if ((lane & 7) == 0) s_sorted[(size_t)pos * 8 + (lane >> 3)] = sg;
                if (lane == 0) src_sorted[pos] = se_[m];
            }
        }
    }
}

// ---------------- aggregation: one wave per node, no atomics ----------------
__global__ __launch_bounds__(256)
void aggregate_kernel(const int* __restrict__ offsets,
                      const int* __restrict__ src_sorted,
                      const float* __restrict__ s_sorted,
                      const float* __restrict__ V,
                      float* __restrict__ hout, int n)
{
    const int w = (blockIdx.x * 256 + threadIdx.x) >> 6;
    const int lane = threadIdx.x & 63;
    if (w >= n) return;
    const int o0 = offsets[w], o1 = offsets[w + 1];
    const int head = lane >> 3;
    float acc = 0.f, zacc = 0.f;
    int j = o0;
    for (; j + 4 <= o1; j += 4) {
        const int sv0 = src_sorted[j + 0];
        const int sv1 = src_sorted[j + 1];
        const int sv2 = src_sorted[j + 2];
        const int sv3 = src_sorted[j + 3];
        const float s0 = s_sorted[(size_t)(j + 0) * 8 + head];
        const float s1 = s_sorted[(size_t)(j + 1) * 8 + head];
        const float s2 = s_sorted[(size_t)(j + 2) * 8 + head];
        const float s3 = s_sorted[(size_t)(j + 3) * 8 + head];
        const float v0 = V[(size_t)sv0 * 64 + lane];
        const float v1 = V[(size_t)sv1 * 64 + lane];
        const float v2 = V[(size_t)sv2 * 64 + lane];
        const float v3 = V[(size_t)sv3 * 64 + lane];
        acc = fmaf(v0, s0, acc);
        acc = fmaf(v1, s1, acc);
        acc = fmaf(v2, s2, acc);
        acc = fmaf(v3, s3, acc);
        zacc += (s0 + s1) + (s2 + s3);
    }
    for (; j < o1; ++j) {
        const int sv = src_sorted[j];
        const float s = s_sorted[(size_t)j * 8 + head];
        acc = fmaf(V[(size_t)sv * 64 + lane], s, acc);
        zacc += s;
    }
    hout[(size_t)w * 64 + lane] = acc / (zacc + 1e-6f);
}

extern "C" void kernel_launch(void* const* d_in, const int* in_sizes, int n_in,
                              void* d_out, int out_size, void* d_ws, size_t ws_size,
                              hipStream_t stream)
{
    const float* h  = (const float*)d_in[0];
    const float* e  = (const float*)d_in[1];
    const float* Wq = (const float*)d_in[2];
    const float* bq = (const float*)d_in[3];
    const float* Wk = (const float*)d_in[4];
    const float* bk = (const float*)d_in[5];
    const float* Wv = (const float*)d_in[6];
    const float* bv = (const float*)d_in[7];
    const float* We = (const float*)d_in[8];
    const float* be = (const float*)d_in[9];
    const int* src  = (const int*)d_in[10];
    const int* dst  = (const int*)d_in[11];

    const int N = in_sizes[0] / 64;
    const int E = in_sizes[1] / 64;

    float* hout  = (float*)d_out;                    // [N*64]
    float* e_out = (float*)d_out + (size_t)N * 64;   // [E*64]

    // workspace layout
    char* ws = (char*)d_ws;
    float* Q = (float*)ws;                 ws += (size_t)N * 64 * sizeof(float);
    float* K = (float*)ws;                 ws += (size_t)N * 64 * sizeof(float);
    float* V = (float*)ws;                 ws += (size_t)N * 64 * sizeof(float);
    float* s_sorted = (float*)ws;          ws += (size_t)E * 8 * sizeof(float);
    int* src_sorted = (int*)ws;            ws += (size_t)E * sizeof(int);
    int* counts  = (int*)ws;               ws += (size_t)N * sizeof(int);
    int* offsets = (int*)ws;               ws += (size_t)(N + 1) * sizeof(int);
    int* cursor  = (int*)ws;               ws += (size_t)N * sizeof(int);

    hipMemsetAsync(counts, 0, (size_t)N * sizeof(int), stream);

    // 1) Q,K,V projections
    proj_kernel<<<dim3(512, 3), dim3(256), 0, stream>>>(
        h, Wq, bq, Wk, bk, Wv, bv, Q, K, V, N);

    // 2) dst histogram
    hist_kernel<<<dim3(2048), dim3(256), 0, stream>>>(dst, counts, E);

    // 3) exclusive scan -> offsets, cursor
    scan_kernel<<<dim3(1), dim3(1024), 0, stream>>>(counts, offsets, cursor, N, E);

    // 4) edge pass: e_out + slot scatter of s / src
    const int egroups = (E + 15) >> 4;
    const int eblocks = egroups < 2048 ? egroups : 2048;
    edge_kernel<<<dim3(eblocks), dim3(256), 0, stream>>>(
        e, We, be, src, dst, Q, K, e_out, s_sorted, src_sorted, cursor, E);

    // 5) aggregate per node (one wave each)
    const int ablocks = (N * 64 + 255) / 256;
    aggregate_kernel<<<dim3(ablocks), dim3(256), 0, stream>>>(
        offsets, src_sorted, s_sorted, V, hout, N);
}

// Round 3
// 1567.048 us; speedup vs baseline: 1.4711x; 1.4711x over previous
//
#include <hip/hip_runtime.h>

// Graph-transformer MHA layer. N=50000, E=1600000, IN_DIM=64, H=8, D=8.
// Outputs: h_out [N*64] then e_out [E*64], fp32, concatenated in d_out.
//
// R3: edge kernel restructured with lane = edge (64 edges per wave-tile).
//  - e row chunks are per-lane loads (L1 absorbs 16B-granule re-touch)
//  - We[k][j] is wave-uniform -> scalar loads (s_load), FMA reads SGPR operand
//  - acc[64] in VGPRs, statically indexed
//  - no LDS, no __syncthreads, no cross-lane ops in the hot loop
//  - per-head sums are per-lane scalar adds; 1 cursor atomic per lane
// Aggregation stays two-phase (hist/scan/slot-scatter/gather) - no RMW atomics.

// ---------------- node projection ----------------
__global__ __launch_bounds__(256)
void proj_kernel(const float* __restrict__ hsrc,
                 const float* __restrict__ Wq, const float* __restrict__ bq,
                 const float* __restrict__ Wk, const float* __restrict__ bk,
                 const float* __restrict__ Wv, const float* __restrict__ bv,
                 float* __restrict__ Q, float* __restrict__ K, float* __restrict__ V,
                 int n)
{
    const float* W;
    const float* b;
    float* out;
    if (blockIdx.y == 0)      { W = Wq; b = bq; out = Q; }
    else if (blockIdx.y == 1) { W = Wk; b = bk; out = K; }
    else                      { W = Wv; b = bv; out = V; }

    const int t    = threadIdx.x;
    const int lane = t & 63;
    const int w    = t >> 6;

    float wcol[64];
#pragma unroll
    for (int k = 0; k < 64; ++k) wcol[k] = W[k * 64 + lane];
    const float bias = b[lane];

    __shared__ float4 sh[16][16];
    const float4* __restrict__ h4 = (const float4*)hsrc;

    const int ngroups = (n + 15) >> 4;
    for (int g = blockIdx.x; g < ngroups; g += gridDim.x) {
        const int base = g << 4;
        {
            const int rs = t >> 4, c4 = t & 15;
            float4 v = make_float4(0.f, 0.f, 0.f, 0.f);
            if (base + rs < n) v = h4[(size_t)(base + rs) * 16 + c4];
            __syncthreads();
            sh[rs][c4] = v;
            __syncthreads();
        }
        float acc0 = bias, acc1 = bias, acc2 = bias, acc3 = bias;
#pragma unroll
        for (int k4 = 0; k4 < 16; ++k4) {
            const float w0 = wcol[k4 * 4 + 0], w1 = wcol[k4 * 4 + 1];
            const float w2 = wcol[k4 * 4 + 2], w3 = wcol[k4 * 4 + 3];
            const float4 a = sh[w * 4 + 0][k4];
            const float4 bb = sh[w * 4 + 1][k4];
            const float4 c = sh[w * 4 + 2][k4];
            const float4 d = sh[w * 4 + 3][k4];
            acc0 = fmaf(a.w,  w3, fmaf(a.z,  w2, fmaf(a.y,  w1, fmaf(a.x,  w0, acc0))));
            acc1 = fmaf(bb.w, w3, fmaf(bb.z, w2, fmaf(bb.y, w1, fmaf(bb.x, w0, acc1))));
            acc2 = fmaf(c.w,  w3, fmaf(c.z,  w2, fmaf(c.y,  w1, fmaf(c.x,  w0, acc2))));
            acc3 = fmaf(d.w,  w3, fmaf(d.z,  w2, fmaf(d.y,  w1, fmaf(d.x,  w0, acc3))));
        }
        const int n0 = base + w * 4;
        if (n0 + 0 < n) out[(size_t)(n0 + 0) * 64 + lane] = acc0;
        if (n0 + 1 < n) out[(size_t)(n0 + 1) * 64 + lane] = acc1;
        if (n0 + 2 < n) out[(size_t)(n0 + 2) * 64 + lane] = acc2;
        if (n0 + 3 < n) out[(size_t)(n0 + 3) * 64 + lane] = acc3;
    }
}

// ---------------- dst histogram ----------------
__global__ __launch_bounds__(256)
void hist_kernel(const int* __restrict__ dst, int* __restrict__ counts, int E)
{
    int i = blockIdx.x * 256 + threadIdx.x;
    const int stride = gridDim.x * 256;
    for (; i < E; i += stride) atomicAdd(&counts[dst[i]], 1);
}

// ---------------- exclusive scan over counts (single block, 1024 thr) ----------------
__global__ __launch_bounds__(1024)
void scan_kernel(const int* __restrict__ counts, int* __restrict__ offsets,
                 int* __restrict__ cursor, int n, int E)
{
    __shared__ int wsum[16];
    const int t = threadIdx.x;
    const int lane = t & 63;
    const int w = t >> 6;
    int carry = 0;
    for (int base = 0; base < n; base += 1024) {
        const int i = base + t;
        const int v = (i < n) ? counts[i] : 0;
        int x = v;
#pragma unroll
        for (int d = 1; d < 64; d <<= 1) {
            int y = __shfl_up(x, d);
            if (lane >= d) x += y;
        }
        if (lane == 63) wsum[w] = x;
        __syncthreads();
        if (w == 0 && lane < 16) {
            int s = wsum[lane];
#pragma unroll
            for (int d = 1; d < 16; d <<= 1) {
                int y = __shfl_up(s, d);
                if (lane >= d) s += y;
            }
            wsum[lane] = s;
        }
        __syncthreads();
        const int woff = (w == 0) ? 0 : wsum[w - 1];
        const int excl = carry + woff + (x - v);
        if (i < n) { offsets[i] = excl; cursor[i] = excl; }
        carry += wsum[15];
        __syncthreads();
    }
    if (t == 0) offsets[n] = E;
}

// ---------------- edge kernel v3: lane = edge ----------------
__global__ __launch_bounds__(256)
void edge_kernel(const float* __restrict__ e,
                 const float* __restrict__ We, const float* __restrict__ be,
                 const int* __restrict__ src, const int* __restrict__ dst,
                 const float* __restrict__ Q, const float* __restrict__ K,
                 float* __restrict__ e_out,
                 float* __restrict__ s_sorted, int* __restrict__ src_sorted,
                 int* __restrict__ cursor, int E)
{
    const int t    = threadIdx.x;
    const int lane = t & 63;
    const int gw   = (blockIdx.x * 256 + t) >> 6;     // global wave id = tile id
    const int ntiles = (E + 63) >> 6;
    if (gw >= ntiles) return;

    const float inv_sqrt_d = 0.35355339059327373f;    // 1/sqrt(8)

    const int eid   = gw * 64 + lane;
    const bool valid = eid < E;
    const int eidc  = valid ? eid : (E - 1);          // clamped for safe addresses

    const int s_ = src[eidc];
    const int d_ = dst[eidc];

    // ---- projection: acc[j] = be[j] + sum_k e[eid][k] * We[k][j] ----
    float acc[64];
#pragma unroll
    for (int j = 0; j < 64; ++j) acc[j] = be[j];      // uniform -> scalar loads

    const float4* __restrict__ erow = (const float4*)(e + (size_t)eidc * 64);
    for (int k4 = 0; k4 < 16; ++k4) {                 // not unrolled: bounds SGPR pressure
        const float4 ev = erow[k4];
#pragma unroll
        for (int kk = 0; kk < 4; ++kk) {
            const float ekv = (kk == 0) ? ev.x : (kk == 1) ? ev.y : (kk == 2) ? ev.z : ev.w;
            const float* __restrict__ wrow = We + (size_t)(k4 * 4 + kk) * 64;
#pragma unroll
            for (int j = 0; j < 64; ++j)
                acc[j] = fmaf(ekv, wrow[j], acc[j]);  // wrow[j] uniform -> SGPR operand
        }
    }

    // ---- score + e_out + per-head sums (all per-lane) ----
    const float4* __restrict__ krow = (const float4*)(K + (size_t)s_ * 64);
    const float4* __restrict__ qrow = (const float4*)(Q + (size_t)d_ * 64);
    float4* __restrict__ orow = (float4*)(e_out + (size_t)eidc * 64);

    float hs[8];
#pragma unroll
    for (int hd = 0; hd < 8; ++hd) hs[hd] = 0.f;

#pragma unroll
    for (int j4 = 0; j4 < 16; ++j4) {
        const float4 kv = krow[j4];
        const float4 qv = qrow[j4];
        float4 sc;
        sc.x = kv.x * qv.x * inv_sqrt_d * acc[j4 * 4 + 0];
        sc.y = kv.y * qv.y * inv_sqrt_d * acc[j4 * 4 + 1];
        sc.z = kv.z * qv.z * inv_sqrt_d * acc[j4 * 4 + 2];
        sc.w = kv.w * qv.w * inv_sqrt_d * acc[j4 * 4 + 3];
        if (valid) orow[j4] = sc;
        hs[j4 >> 1] += (sc.x + sc.y) + (sc.z + sc.w);
    }

    // ---- per-head gate + slot scatter ----
    float sg[8];
#pragma unroll
    for (int hd = 0; hd < 8; ++hd)
        sg[hd] = expf(fminf(fmaxf(hs[hd], -5.f), 5.f));

    if (valid) {
        const int pos = atomicAdd(&cursor[d_], 1);
        src_sorted[pos] = s_;
        float4* srow = (float4*)(s_sorted + (size_t)pos * 8);
        srow[0] = make_float4(sg[0], sg[1], sg[2], sg[3]);
        srow[1] = make_float4(sg[4], sg[5], sg[6], sg[7]);
    }
}

// ---------------- aggregation: one wave per node, no atomics ----------------
__global__ __launch_bounds__(256)
void aggregate_kernel(const int* __restrict__ offsets,
                      const int* __restrict__ src_sorted,
                      const float* __restrict__ s_sorted,
                      const float* __restrict__ V,
                      float* __restrict__ hout, int n)
{
    const int w = (blockIdx.x * 256 + threadIdx.x) >> 6;
    const int lane = threadIdx.x & 63;
    if (w >= n) return;
    const int o0 = offsets[w], o1 = offsets[w + 1];
    const int head = lane >> 3;
    float acc = 0.f, zacc = 0.f;
    int j = o0;
    for (; j + 4 <= o1; j += 4) {
        const int sv0 = src_sorted[j + 0];
        const int sv1 = src_sorted[j + 1];
        const int sv2 = src_sorted[j + 2];
        const int sv3 = src_sorted[j + 3];
        const float s0 = s_sorted[(size_t)(j + 0) * 8 + head];
        const float s1 = s_sorted[(size_t)(j + 1) * 8 + head];
        const float s2 = s_sorted[(size_t)(j + 2) * 8 + head];
        const float s3 = s_sorted[(size_t)(j + 3) * 8 + head];
        const float v0 = V[(size_t)sv0 * 64 + lane];
        const float v1 = V[(size_t)sv1 * 64 + lane];
        const float v2 = V[(size_t)sv2 * 64 + lane];
        const float v3 = V[(size_t)sv3 * 64 + lane];
        acc = fmaf(v0, s0, acc);
        acc = fmaf(v1, s1, acc);
        acc = fmaf(v2, s2, acc);
        acc = fmaf(v3, s3, acc);
        zacc += (s0 + s1) + (s2 + s3);
    }
    for (; j < o1; ++j) {
        const int sv = src_sorted[j];
        const float s = s_sorted[(size_t)j * 8 + head];
        acc = fmaf(V[(size_t)sv * 64 + lane], s, acc);
        zacc += s;
    }
    hout[(size_t)w * 64 + lane] = acc / (zacc + 1e-6f);
}

extern "C" void kernel_launch(void* const* d_in, const int* in_sizes, int n_in,
                              void* d_out, int out_size, void* d_ws, size_t ws_size,
                              hipStream_t stream)
{
    const float* h  = (const float*)d_in[0];
    const float* e  = (const float*)d_in[1];
    const float* Wq = (const float*)d_in[2];
    const float* bq = (const float*)d_in[3];
    const float* Wk = (const float*)d_in[4];
    const float* bk = (const float*)d_in[5];
    const float* Wv = (const float*)d_in[6];
    const float* bv = (const float*)d_in[7];
    const float* We = (const float*)d_in[8];
    const float* be = (const float*)d_in[9];
    const int* src  = (const int*)d_in[10];
    const int* dst  = (const int*)d_in[11];

    const int N = in_sizes[0] / 64;
    const int E = in_sizes[1] / 64;

    float* hout  = (float*)d_out;                    // [N*64]
    float* e_out = (float*)d_out + (size_t)N * 64;   // [E*64]

    // workspace layout
    char* ws = (char*)d_ws;
    float* Q = (float*)ws;                 ws += (size_t)N * 64 * sizeof(float);
    float* K = (float*)ws;                 ws += (size_t)N * 64 * sizeof(float);
    float* V = (float*)ws;                 ws += (size_t)N * 64 * sizeof(float);
    float* s_sorted = (float*)ws;          ws += (size_t)E * 8 * sizeof(float);
    int* src_sorted = (int*)ws;            ws += (size_t)E * sizeof(int);
    int* counts  = (int*)ws;               ws += (size_t)N * sizeof(int);
    int* offsets = (int*)ws;               ws += (size_t)(N + 1) * sizeof(int);
    int* cursor  = (int*)ws;               ws += (size_t)N * sizeof(int);

    hipMemsetAsync(counts, 0, (size_t)N * sizeof(int), stream);

    // 1) Q,K,V projections
    proj_kernel<<<dim3(512, 3), dim3(256), 0, stream>>>(
        h, Wq, bq, Wk, bk, Wv, bv, Q, K, V, N);

    // 2) dst histogram
    hist_kernel<<<dim3(2048), dim3(256), 0, stream>>>(dst, counts, E);

    // 3) exclusive scan -> offsets, cursor
    scan_kernel<<<dim3(1), dim3(1024), 0, stream>>>(counts, offsets, cursor, N, E);

    // 4) edge pass: lane = edge; 64 edges per wave
    const int ntiles = (E + 63) >> 6;               // 25000 wave-tiles
    const int eblocks = (ntiles + 3) / 4;           // 4 waves per block
    edge_kernel<<<dim3(eblocks), dim3(256), 0, stream>>>(
        e, We, be, src, dst, Q, K, e_out, s_sorted, src_sorted, cursor, E);

    // 5) aggregate per node (one wave each)
    const int ablocks = (N * 64 + 255) / 256;
    aggregate_kernel<<<dim3(ablocks), dim3(256), 0, stream>>>(
        offsets, src_sorted, s_sorted, V, hout, N);
}

// Round 4
// 787.569 us; speedup vs baseline: 2.9271x; 1.9897x over previous
//
#include <hip/hip_runtime.h>

// Graph-transformer MHA layer. N=50000, E=1600000, IN_DIM=64, H=8, D=8.
// Outputs: h_out [N*64] then e_out [E*64], fp32, concatenated in d_out.
//
// R4: lane = edge, but ALL hot state in named variables (no local arrays ->
// nothing the compiler can demote to scratch; R3's acc[64] went to scratch:
// VGPR=48, FETCH 3.5GB, VALU 8%).
//  - e row loaded once into 16 named float4s (64 VGPR)
//  - output j-dim processed in 4 chunks of 16 (4 named float4 accumulators)
//  - We[k][j] wave-uniform -> scalar loads feed v_fma SGPR operand
//  - per chunk: fused K/Q score, e_out store (4 contiguous float4s = 64B/lane
//    back-to-back -> L2 write merge), head partial sums
//  - 1 cursor atomic per lane (edge)

// ---------------- node projection ----------------
__global__ __launch_bounds__(256)
void proj_kernel(const float* __restrict__ hsrc,
                 const float* __restrict__ Wq, const float* __restrict__ bq,
                 const float* __restrict__ Wk, const float* __restrict__ bk,
                 const float* __restrict__ Wv, const float* __restrict__ bv,
                 float* __restrict__ Q, float* __restrict__ K, float* __restrict__ V,
                 int n)
{
    const float* W;
    const float* b;
    float* out;
    if (blockIdx.y == 0)      { W = Wq; b = bq; out = Q; }
    else if (blockIdx.y == 1) { W = Wk; b = bk; out = K; }
    else                      { W = Wv; b = bv; out = V; }

    const int t    = threadIdx.x;
    const int lane = t & 63;
    const int w    = t >> 6;

    float wcol[64];
#pragma unroll
    for (int k = 0; k < 64; ++k) wcol[k] = W[k * 64 + lane];
    const float bias = b[lane];

    __shared__ float4 sh[16][16];
    const float4* __restrict__ h4 = (const float4*)hsrc;

    const int ngroups = (n + 15) >> 4;
    for (int g = blockIdx.x; g < ngroups; g += gridDim.x) {
        const int base = g << 4;
        {
            const int rs = t >> 4, c4 = t & 15;
            float4 v = make_float4(0.f, 0.f, 0.f, 0.f);
            if (base + rs < n) v = h4[(size_t)(base + rs) * 16 + c4];
            __syncthreads();
            sh[rs][c4] = v;
            __syncthreads();
        }
        float acc0 = bias, acc1 = bias, acc2 = bias, acc3 = bias;
#pragma unroll
        for (int k4 = 0; k4 < 16; ++k4) {
            const float w0 = wcol[k4 * 4 + 0], w1 = wcol[k4 * 4 + 1];
            const float w2 = wcol[k4 * 4 + 2], w3 = wcol[k4 * 4 + 3];
            const float4 a = sh[w * 4 + 0][k4];
            const float4 bb = sh[w * 4 + 1][k4];
            const float4 c = sh[w * 4 + 2][k4];
            const float4 d = sh[w * 4 + 3][k4];
            acc0 = fmaf(a.w,  w3, fmaf(a.z,  w2, fmaf(a.y,  w1, fmaf(a.x,  w0, acc0))));
            acc1 = fmaf(bb.w, w3, fmaf(bb.z, w2, fmaf(bb.y, w1, fmaf(bb.x, w0, acc1))));
            acc2 = fmaf(c.w,  w3, fmaf(c.z,  w2, fmaf(c.y,  w1, fmaf(c.x,  w0, acc2))));
            acc3 = fmaf(d.w,  w3, fmaf(d.z,  w2, fmaf(d.y,  w1, fmaf(d.x,  w0, acc3))));
        }
        const int n0 = base + w * 4;
        if (n0 + 0 < n) out[(size_t)(n0 + 0) * 64 + lane] = acc0;
        if (n0 + 1 < n) out[(size_t)(n0 + 1) * 64 + lane] = acc1;
        if (n0 + 2 < n) out[(size_t)(n0 + 2) * 64 + lane] = acc2;
        if (n0 + 3 < n) out[(size_t)(n0 + 3) * 64 + lane] = acc3;
    }
}

// ---------------- dst histogram ----------------
__global__ __launch_bounds__(256)
void hist_kernel(const int* __restrict__ dst, int* __restrict__ counts, int E)
{
    int i = blockIdx.x * 256 + threadIdx.x;
    const int stride = gridDim.x * 256;
    for (; i < E; i += stride) atomicAdd(&counts[dst[i]], 1);
}

// ---------------- exclusive scan over counts (single block, 1024 thr) ----------------
__global__ __launch_bounds__(1024)
void scan_kernel(const int* __restrict__ counts, int* __restrict__ offsets,
                 int* __restrict__ cursor, int n, int E)
{
    __shared__ int wsum[16];
    const int t = threadIdx.x;
    const int lane = t & 63;
    const int w = t >> 6;
    int carry = 0;
    for (int base = 0; base < n; base += 1024) {
        const int i = base + t;
        const int v = (i < n) ? counts[i] : 0;
        int x = v;
#pragma unroll
        for (int d = 1; d < 64; d <<= 1) {
            int y = __shfl_up(x, d);
            if (lane >= d) x += y;
        }
        if (lane == 63) wsum[w] = x;
        __syncthreads();
        if (w == 0 && lane < 16) {
            int s = wsum[lane];
#pragma unroll
            for (int d = 1; d < 16; d <<= 1) {
                int y = __shfl_up(s, d);
                if (lane >= d) s += y;
            }
            wsum[lane] = s;
        }
        __syncthreads();
        const int woff = (w == 0) ? 0 : wsum[w - 1];
        const int excl = carry + woff + (x - v);
        if (i < n) { offsets[i] = excl; cursor[i] = excl; }
        carry += wsum[15];
        __syncthreads();
    }
    if (t == 0) offsets[n] = E;
}

// 16 FMAs of uniform We values into 4 named float4 accumulators
#define FMA16(s, W) do { \
    const float* _w = (W); \
    accA.x = fmaf((s), _w[0],  accA.x); accA.y = fmaf((s), _w[1],  accA.y); \
    accA.z = fmaf((s), _w[2],  accA.z); accA.w = fmaf((s), _w[3],  accA.w); \
    accB.x = fmaf((s), _w[4],  accB.x); accB.y = fmaf((s), _w[5],  accB.y); \
    accB.z = fmaf((s), _w[6],  accB.z); accB.w = fmaf((s), _w[7],  accB.w); \
    accC.x = fmaf((s), _w[8],  accC.x); accC.y = fmaf((s), _w[9],  accC.y); \
    accC.z = fmaf((s), _w[10], accC.z); accC.w = fmaf((s), _w[11], accC.w); \
    accD.x = fmaf((s), _w[12], accD.x); accD.y = fmaf((s), _w[13], accD.y); \
    accD.z = fmaf((s), _w[14], accD.z); accD.w = fmaf((s), _w[15], accD.w); \
} while (0)

#define K4X(EV, kb) \
    FMA16((EV).x, Wc + (kb + 0) * 64); \
    FMA16((EV).y, Wc + (kb + 1) * 64); \
    FMA16((EV).z, Wc + (kb + 2) * 64); \
    FMA16((EV).w, Wc + (kb + 3) * 64);

// one j-chunk: 16 output dims = heads 2c (low) and 2c+1 (high)
#define CHUNK(c, HSL, HSH) do { \
    const float* Wc = We + (c) * 16; \
    const float4* be4 = (const float4*)(be + (c) * 16); \
    float4 accA = be4[0], accB = be4[1], accC = be4[2], accD = be4[3]; \
    K4X(ev0, 0)   K4X(ev1, 4)   K4X(ev2, 8)   K4X(ev3, 12) \
    K4X(ev4, 16)  K4X(ev5, 20)  K4X(ev6, 24)  K4X(ev7, 28) \
    K4X(ev8, 32)  K4X(ev9, 36)  K4X(ev10, 40) K4X(ev11, 44) \
    K4X(ev12, 48) K4X(ev13, 52) K4X(ev14, 56) K4X(ev15, 60) \
    const float4 kv0 = krow[(c)*4+0], kv1 = krow[(c)*4+1]; \
    const float4 kv2 = krow[(c)*4+2], kv3 = krow[(c)*4+3]; \
    const float4 qv0 = qrow[(c)*4+0], qv1 = qrow[(c)*4+1]; \
    const float4 qv2 = qrow[(c)*4+2], qv3 = qrow[(c)*4+3]; \
    float4 s0, s1, s2, s3; \
    s0.x = kv0.x*qv0.x*inv_sqrt_d*accA.x; s0.y = kv0.y*qv0.y*inv_sqrt_d*accA.y; \
    s0.z = kv0.z*qv0.z*inv_sqrt_d*accA.z; s0.w = kv0.w*qv0.w*inv_sqrt_d*accA.w; \
    s1.x = kv1.x*qv1.x*inv_sqrt_d*accB.x; s1.y = kv1.y*qv1.y*inv_sqrt_d*accB.y; \
    s1.z = kv1.z*qv1.z*inv_sqrt_d*accB.z; s1.w = kv1.w*qv1.w*inv_sqrt_d*accB.w; \
    s2.x = kv2.x*qv2.x*inv_sqrt_d*accC.x; s2.y = kv2.y*qv2.y*inv_sqrt_d*accC.y; \
    s2.z = kv2.z*qv2.z*inv_sqrt_d*accC.z; s2.w = kv2.w*qv2.w*inv_sqrt_d*accC.w; \
    s3.x = kv3.x*qv3.x*inv_sqrt_d*accD.x; s3.y = kv3.y*qv3.y*inv_sqrt_d*accD.y; \
    s3.z = kv3.z*qv3.z*inv_sqrt_d*accD.z; s3.w = kv3.w*qv3.w*inv_sqrt_d*accD.w; \
    if (valid) { \
        orow[(c)*4+0] = s0; orow[(c)*4+1] = s1; \
        orow[(c)*4+2] = s2; orow[(c)*4+3] = s3; \
    } \
    HSL = ((s0.x+s0.y)+(s0.z+s0.w)) + ((s1.x+s1.y)+(s1.z+s1.w)); \
    HSH = ((s2.x+s2.y)+(s2.z+s2.w)) + ((s3.x+s3.y)+(s3.z+s3.w)); \
} while (0)

// ---------------- edge kernel v4: lane = edge, named regs only ----------------
__global__ __launch_bounds__(256)
void edge_kernel(const float* __restrict__ e,
                 const float* __restrict__ We, const float* __restrict__ be,
                 const int* __restrict__ src, const int* __restrict__ dst,
                 const float* __restrict__ Q, const float* __restrict__ K,
                 float* __restrict__ e_out,
                 float* __restrict__ s_sorted, int* __restrict__ src_sorted,
                 int* __restrict__ cursor, int E)
{
    const int t    = threadIdx.x;
    const int lane = t & 63;
    const int gw   = (blockIdx.x * 256 + t) >> 6;
    const int ntiles = (E + 63) >> 6;
    if (gw >= ntiles) return;

    const float inv_sqrt_d = 0.35355339059327373f;    // 1/sqrt(8)

    const int eid   = gw * 64 + lane;
    const bool valid = eid < E;
    const int eidc  = valid ? eid : (E - 1);

    const int s_ = src[eidc];
    const int d_ = dst[eidc];

    // e row -> 16 named float4s (stays in VGPRs; nothing to demote)
    const float4* __restrict__ erow = (const float4*)(e + (size_t)eidc * 64);
    const float4 ev0 = erow[0],  ev1 = erow[1],  ev2 = erow[2],  ev3 = erow[3];
    const float4 ev4 = erow[4],  ev5 = erow[5],  ev6 = erow[6],  ev7 = erow[7];
    const float4 ev8 = erow[8],  ev9 = erow[9],  ev10 = erow[10], ev11 = erow[11];
    const float4 ev12 = erow[12], ev13 = erow[13], ev14 = erow[14], ev15 = erow[15];

    const float4* __restrict__ krow = (const float4*)(K + (size_t)s_ * 64);
    const float4* __restrict__ qrow = (const float4*)(Q + (size_t)d_ * 64);
    float4* __restrict__ orow = (float4*)(e_out + (size_t)eidc * 64);

    float hs0, hs1, hs2, hs3, hs4, hs5, hs6, hs7;
    CHUNK(0, hs0, hs1);
    CHUNK(1, hs2, hs3);
    CHUNK(2, hs4, hs5);
    CHUNK(3, hs6, hs7);

    const float g0 = expf(fminf(fmaxf(hs0, -5.f), 5.f));
    const float g1 = expf(fminf(fmaxf(hs1, -5.f), 5.f));
    const float g2 = expf(fminf(fmaxf(hs2, -5.f), 5.f));
    const float g3 = expf(fminf(fmaxf(hs3, -5.f), 5.f));
    const float g4 = expf(fminf(fmaxf(hs4, -5.f), 5.f));
    const float g5 = expf(fminf(fmaxf(hs5, -5.f), 5.f));
    const float g6 = expf(fminf(fmaxf(hs6, -5.f), 5.f));
    const float g7 = expf(fminf(fmaxf(hs7, -5.f), 5.f));

    if (valid) {
        const int pos = atomicAdd(&cursor[d_], 1);
        src_sorted[pos] = s_;
        float4* srow = (float4*)(s_sorted + (size_t)pos * 8);
        srow[0] = make_float4(g0, g1, g2, g3);
        srow[1] = make_float4(g4, g5, g6, g7);
    }
}

// ---------------- aggregation: one wave per node, no atomics ----------------
__global__ __launch_bounds__(256)
void aggregate_kernel(const int* __restrict__ offsets,
                      const int* __restrict__ src_sorted,
                      const float* __restrict__ s_sorted,
                      const float* __restrict__ V,
                      float* __restrict__ hout, int n)
{
    const int w = (blockIdx.x * 256 + threadIdx.x) >> 6;
    const int lane = threadIdx.x & 63;
    if (w >= n) return;
    const int o0 = offsets[w], o1 = offsets[w + 1];
    const int head = lane >> 3;
    float acc = 0.f, zacc = 0.f;
    int j = o0;
    for (; j + 4 <= o1; j += 4) {
        const int sv0 = src_sorted[j + 0];
        const int sv1 = src_sorted[j + 1];
        const int sv2 = src_sorted[j + 2];
        const int sv3 = src_sorted[j + 3];
        const float s0 = s_sorted[(size_t)(j + 0) * 8 + head];
        const float s1 = s_sorted[(size_t)(j + 1) * 8 + head];
        const float s2 = s_sorted[(size_t)(j + 2) * 8 + head];
        const float s3 = s_sorted[(size_t)(j + 3) * 8 + head];
        const float v0 = V[(size_t)sv0 * 64 + lane];
        const float v1 = V[(size_t)sv1 * 64 + lane];
        const float v2 = V[(size_t)sv2 * 64 + lane];
        const float v3 = V[(size_t)sv3 * 64 + lane];
        acc = fmaf(v0, s0, acc);
        acc = fmaf(v1, s1, acc);
        acc = fmaf(v2, s2, acc);
        acc = fmaf(v3, s3, acc);
        zacc += (s0 + s1) + (s2 + s3);
    }
    for (; j < o1; ++j) {
        const int sv = src_sorted[j];
        const float s = s_sorted[(size_t)j * 8 + head];
        acc = fmaf(V[(size_t)sv * 64 + lane], s, acc);
        zacc += s;
    }
    hout[(size_t)w * 64 + lane] = acc / (zacc + 1e-6f);
}

extern "C" void kernel_launch(void* const* d_in, const int* in_sizes, int n_in,
                              void* d_out, int out_size, void* d_ws, size_t ws_size,
                              hipStream_t stream)
{
    const float* h  = (const float*)d_in[0];
    const float* e  = (const float*)d_in[1];
    const float* Wq = (const float*)d_in[2];
    const float* bq = (const float*)d_in[3];
    const float* Wk = (const float*)d_in[4];
    const float* bk = (const float*)d_in[5];
    const float* Wv = (const float*)d_in[6];
    const float* bv = (const float*)d_in[7];
    const float* We = (const float*)d_in[8];
    const float* be = (const float*)d_in[9];
    const int* src  = (const int*)d_in[10];
    const int* dst  = (const int*)d_in[11];

    const int N = in_sizes[0] / 64;
    const int E = in_sizes[1] / 64;

    float* hout  = (float*)d_out;                    // [N*64]
    float* e_out = (float*)d_out + (size_t)N * 64;   // [E*64]

    // workspace layout
    char* ws = (char*)d_ws;
    float* Q = (float*)ws;                 ws += (size_t)N * 64 * sizeof(float);
    float* K = (float*)ws;                 ws += (size_t)N * 64 * sizeof(float);
    float* V = (float*)ws;                 ws += (size_t)N * 64 * sizeof(float);
    float* s_sorted = (float*)ws;          ws += (size_t)E * 8 * sizeof(float);
    int* src_sorted = (int*)ws;            ws += (size_t)E * sizeof(int);
    int* counts  = (int*)ws;               ws += (size_t)N * sizeof(int);
    int* offsets = (int*)ws;               ws += (size_t)(N + 1) * sizeof(int);
    int* cursor  = (int*)ws;               ws += (size_t)N * sizeof(int);

    hipMemsetAsync(counts, 0, (size_t)N * sizeof(int), stream);

    // 1) Q,K,V projections
    proj_kernel<<<dim3(512, 3), dim3(256), 0, stream>>>(
        h, Wq, bq, Wk, bk, Wv, bv, Q, K, V, N);

    // 2) dst histogram
    hist_kernel<<<dim3(2048), dim3(256), 0, stream>>>(dst, counts, E);

    // 3) exclusive scan -> offsets, cursor
    scan_kernel<<<dim3(1), dim3(1024), 0, stream>>>(counts, offsets, cursor, N, E);

    // 4) edge pass: lane = edge; 64 edges per wave
    const int ntiles = (E + 63) >> 6;               // 25000 wave-tiles
    const int eblocks = (ntiles + 3) / 4;           // 4 waves per block
    edge_kernel<<<dim3(eblocks), dim3(256), 0, stream>>>(
        e, We, be, src, dst, Q, K, e_out, s_sorted, src_sorted, cursor, E);

    // 5) aggregate per node (one wave each)
    const int ablocks = (N * 64 + 255) / 256;
    aggregate_kernel<<<dim3(ablocks), dim3(256), 0, stream>>>(
        offsets, src_sorted, s_sorted, V, hout, N);
}

// Round 5
// 736.193 us; speedup vs baseline: 3.1314x; 1.0698x over previous
//
#include <hip/hip_runtime.h>

// Graph-transformer MHA layer. N=50000, E=1600000, IN_DIM=64, H=8, D=8.
// Outputs: h_out [N*64] then e_out [E*64], fp32, concatenated in d_out.
//
// R5: lane = edge; e_out staged in a 16KB per-wave LDS tile (XOR-swizzled
// columns) and written back transposed as fully-coalesced dwordx4 stores
// (64 lanes x 16B contiguous per instruction = full 128B lines -> kills the
// write-allocate RFO that cost ~530MB of FETCH in R4). kv/qv gathers issued
// BEFORE each chunk's 1024-FMA block so the FMA stream hides gather latency.

// ---------------- node projection ----------------
__global__ __launch_bounds__(256)
void proj_kernel(const float* __restrict__ hsrc,
                 const float* __restrict__ Wq, const float* __restrict__ bq,
                 const float* __restrict__ Wk, const float* __restrict__ bk,
                 const float* __restrict__ Wv, const float* __restrict__ bv,
                 float* __restrict__ Q, float* __restrict__ K, float* __restrict__ V,
                 int n)
{
    const float* W;
    const float* b;
    float* out;
    if (blockIdx.y == 0)      { W = Wq; b = bq; out = Q; }
    else if (blockIdx.y == 1) { W = Wk; b = bk; out = K; }
    else                      { W = Wv; b = bv; out = V; }

    const int t    = threadIdx.x;
    const int lane = t & 63;
    const int w    = t >> 6;

    float wcol[64];
#pragma unroll
    for (int k = 0; k < 64; ++k) wcol[k] = W[k * 64 + lane];
    const float bias = b[lane];

    __shared__ float4 sh[16][16];
    const float4* __restrict__ h4 = (const float4*)hsrc;

    const int ngroups = (n + 15) >> 4;
    for (int g = blockIdx.x; g < ngroups; g += gridDim.x) {
        const int base = g << 4;
        {
            const int rs = t >> 4, c4 = t & 15;
            float4 v = make_float4(0.f, 0.f, 0.f, 0.f);
            if (base + rs < n) v = h4[(size_t)(base + rs) * 16 + c4];
            __syncthreads();
            sh[rs][c4] = v;
            __syncthreads();
        }
        float acc0 = bias, acc1 = bias, acc2 = bias, acc3 = bias;
#pragma unroll
        for (int k4 = 0; k4 < 16; ++k4) {
            const float w0 = wcol[k4 * 4 + 0], w1 = wcol[k4 * 4 + 1];
            const float w2 = wcol[k4 * 4 + 2], w3 = wcol[k4 * 4 + 3];
            const float4 a = sh[w * 4 + 0][k4];
            const float4 bb = sh[w * 4 + 1][k4];
            const float4 c = sh[w * 4 + 2][k4];
            const float4 d = sh[w * 4 + 3][k4];
            acc0 = fmaf(a.w,  w3, fmaf(a.z,  w2, fmaf(a.y,  w1, fmaf(a.x,  w0, acc0))));
            acc1 = fmaf(bb.w, w3, fmaf(bb.z, w2, fmaf(bb.y, w1, fmaf(bb.x, w0, acc1))));
            acc2 = fmaf(c.w,  w3, fmaf(c.z,  w2, fmaf(c.y,  w1, fmaf(c.x,  w0, acc2))));
            acc3 = fmaf(d.w,  w3, fmaf(d.z,  w2, fmaf(d.y,  w1, fmaf(d.x,  w0, acc3))));
        }
        const int n0 = base + w * 4;
        if (n0 + 0 < n) out[(size_t)(n0 + 0) * 64 + lane] = acc0;
        if (n0 + 1 < n) out[(size_t)(n0 + 1) * 64 + lane] = acc1;
        if (n0 + 2 < n) out[(size_t)(n0 + 2) * 64 + lane] = acc2;
        if (n0 + 3 < n) out[(size_t)(n0 + 3) * 64 + lane] = acc3;
    }
}

// ---------------- dst histogram ----------------
__global__ __launch_bounds__(256)
void hist_kernel(const int* __restrict__ dst, int* __restrict__ counts, int E)
{
    int i = blockIdx.x * 256 + threadIdx.x;
    const int stride = gridDim.x * 256;
    for (; i < E; i += stride) atomicAdd(&counts[dst[i]], 1);
}

// ---------------- exclusive scan over counts (single block, 1024 thr) ----------------
__global__ __launch_bounds__(1024)
void scan_kernel(const int* __restrict__ counts, int* __restrict__ offsets,
                 int* __restrict__ cursor, int n, int E)
{
    __shared__ int wsum[16];
    const int t = threadIdx.x;
    const int lane = t & 63;
    const int w = t >> 6;
    int carry = 0;
    for (int base = 0; base < n; base += 1024) {
        const int i = base + t;
        const int v = (i < n) ? counts[i] : 0;
        int x = v;
#pragma unroll
        for (int d = 1; d < 64; d <<= 1) {
            int y = __shfl_up(x, d);
            if (lane >= d) x += y;
        }
        if (lane == 63) wsum[w] = x;
        __syncthreads();
        if (w == 0 && lane < 16) {
            int s = wsum[lane];
#pragma unroll
            for (int d = 1; d < 16; d <<= 1) {
                int y = __shfl_up(s, d);
                if (lane >= d) s += y;
            }
            wsum[lane] = s;
        }
        __syncthreads();
        const int woff = (w == 0) ? 0 : wsum[w - 1];
        const int excl = carry + woff + (x - v);
        if (i < n) { offsets[i] = excl; cursor[i] = excl; }
        carry += wsum[15];
        __syncthreads();
    }
    if (t == 0) offsets[n] = E;
}

// 16 FMAs of uniform We values into 4 named float4 accumulators
#define FMA16(s, W) do { \
    const float* _w = (W); \
    accA.x = fmaf((s), _w[0],  accA.x); accA.y = fmaf((s), _w[1],  accA.y); \
    accA.z = fmaf((s), _w[2],  accA.z); accA.w = fmaf((s), _w[3],  accA.w); \
    accB.x = fmaf((s), _w[4],  accB.x); accB.y = fmaf((s), _w[5],  accB.y); \
    accB.z = fmaf((s), _w[6],  accB.z); accB.w = fmaf((s), _w[7],  accB.w); \
    accC.x = fmaf((s), _w[8],  accC.x); accC.y = fmaf((s), _w[9],  accC.y); \
    accC.z = fmaf((s), _w[10], accC.z); accC.w = fmaf((s), _w[11], accC.w); \
    accD.x = fmaf((s), _w[12], accD.x); accD.y = fmaf((s), _w[13], accD.y); \
    accD.z = fmaf((s), _w[14], accD.z); accD.w = fmaf((s), _w[15], accD.w); \
} while (0)

#define K4X(EV, kb) \
    FMA16((EV).x, Wc + (kb + 0) * 64); \
    FMA16((EV).y, Wc + (kb + 1) * 64); \
    FMA16((EV).z, Wc + (kb + 2) * 64); \
    FMA16((EV).w, Wc + (kb + 3) * 64);

// one j-chunk: 16 output dims = heads 2c (low) and 2c+1 (high).
// kv/qv gather loads issued FIRST so the 1024-FMA block hides their latency.
// Scores staged to the XOR-swizzled LDS tile instead of stored to global.
#define CHUNK(c, HSL, HSH) do { \
    const float4 kv0 = krow[(c)*4+0], kv1 = krow[(c)*4+1]; \
    const float4 kv2 = krow[(c)*4+2], kv3 = krow[(c)*4+3]; \
    const float4 qv0 = qrow[(c)*4+0], qv1 = qrow[(c)*4+1]; \
    const float4 qv2 = qrow[(c)*4+2], qv3 = qrow[(c)*4+3]; \
    const float* Wc = We + (c) * 16; \
    const float4* be4 = (const float4*)(be + (c) * 16); \
    float4 accA = be4[0], accB = be4[1], accC = be4[2], accD = be4[3]; \
    K4X(ev0, 0)   K4X(ev1, 4)   K4X(ev2, 8)   K4X(ev3, 12) \
    K4X(ev4, 16)  K4X(ev5, 20)  K4X(ev6, 24)  K4X(ev7, 28) \
    K4X(ev8, 32)  K4X(ev9, 36)  K4X(ev10, 40) K4X(ev11, 44) \
    K4X(ev12, 48) K4X(ev13, 52) K4X(ev14, 56) K4X(ev15, 60) \
    float4 s0, s1, s2, s3; \
    s0.x = kv0.x*qv0.x*inv_sqrt_d*accA.x; s0.y = kv0.y*qv0.y*inv_sqrt_d*accA.y; \
    s0.z = kv0.z*qv0.z*inv_sqrt_d*accA.z; s0.w = kv0.w*qv0.w*inv_sqrt_d*accA.w; \
    s1.x = kv1.x*qv1.x*inv_sqrt_d*accB.x; s1.y = kv1.y*qv1.y*inv_sqrt_d*accB.y; \
    s1.z = kv1.z*qv1.z*inv_sqrt_d*accB.z; s1.w = kv1.w*qv1.w*inv_sqrt_d*accB.w; \
    s2.x = kv2.x*qv2.x*inv_sqrt_d*accC.x; s2.y = kv2.y*qv2.y*inv_sqrt_d*accC.y; \
    s2.z = kv2.z*qv2.z*inv_sqrt_d*accC.z; s2.w = kv2.w*qv2.w*inv_sqrt_d*accC.w; \
    s3.x = kv3.x*qv3.x*inv_sqrt_d*accD.x; s3.y = kv3.y*qv3.y*inv_sqrt_d*accD.y; \
    s3.z = kv3.z*qv3.z*inv_sqrt_d*accD.z; s3.w = kv3.w*qv3.w*inv_sqrt_d*accD.w; \
    tile4[lane * 16 + (((c)*4+0) ^ lx)] = s0; \
    tile4[lane * 16 + (((c)*4+1) ^ lx)] = s1; \
    tile4[lane * 16 + (((c)*4+2) ^ lx)] = s2; \
    tile4[lane * 16 + (((c)*4+3) ^ lx)] = s3; \
    HSL = ((s0.x+s0.y)+(s0.z+s0.w)) + ((s1.x+s1.y)+(s1.z+s1.w)); \
    HSH = ((s2.x+s2.y)+(s2.z+s2.w)) + ((s3.x+s3.y)+(s3.z+s3.w)); \
} while (0)

// ---------------- edge kernel v5: lane = edge, LDS-transposed e_out ----------------
__global__ __launch_bounds__(64)
void edge_kernel(const float* __restrict__ e,
                 const float* __restrict__ We, const float* __restrict__ be,
                 const int* __restrict__ src, const int* __restrict__ dst,
                 const float* __restrict__ Q, const float* __restrict__ K,
                 float* __restrict__ e_out,
                 float* __restrict__ s_sorted, int* __restrict__ src_sorted,
                 int* __restrict__ cursor, int E)
{
    __shared__ float4 tile4[64 * 16];                 // 16 KB; cols XOR-swizzled by lane&15

    const int lane = threadIdx.x;                     // 0..63, one wave per block
    const int base = blockIdx.x * 64;
    if (base >= E) return;

    const float inv_sqrt_d = 0.35355339059327373f;    // 1/sqrt(8)

    const int eid   = base + lane;
    const bool valid = eid < E;
    const int eidc  = valid ? eid : (E - 1);
    const int lx    = lane & 15;

    const int s_ = src[eidc];
    const int d_ = dst[eidc];

    // e row -> 16 named float4s
    const float4* __restrict__ erow = (const float4*)(e + (size_t)eidc * 64);
    const float4 ev0 = erow[0],  ev1 = erow[1],  ev2 = erow[2],  ev3 = erow[3];
    const float4 ev4 = erow[4],  ev5 = erow[5],  ev6 = erow[6],  ev7 = erow[7];
    const float4 ev8 = erow[8],  ev9 = erow[9],  ev10 = erow[10], ev11 = erow[11];
    const float4 ev12 = erow[12], ev13 = erow[13], ev14 = erow[14], ev15 = erow[15];

    const float4* __restrict__ krow = (const float4*)(K + (size_t)s_ * 64);
    const float4* __restrict__ qrow = (const float4*)(Q + (size_t)d_ * 64);

    float hs0, hs1, hs2, hs3, hs4, hs5, hs6, hs7;
    CHUNK(0, hs0, hs1);
    CHUNK(1, hs2, hs3);
    CHUNK(2, hs4, hs5);
    CHUNK(3, hs6, hs7);

    const float g0 = expf(fminf(fmaxf(hs0, -5.f), 5.f));
    const float g1 = expf(fminf(fmaxf(hs1, -5.f), 5.f));
    const float g2 = expf(fminf(fmaxf(hs2, -5.f), 5.f));
    const float g3 = expf(fminf(fmaxf(hs3, -5.f), 5.f));
    const float g4 = expf(fminf(fmaxf(hs4, -5.f), 5.f));
    const float g5 = expf(fminf(fmaxf(hs5, -5.f), 5.f));
    const float g6 = expf(fminf(fmaxf(hs6, -5.f), 5.f));
    const float g7 = expf(fminf(fmaxf(hs7, -5.f), 5.f));

    if (valid) {
        const int pos = atomicAdd(&cursor[d_], 1);
        src_sorted[pos] = s_;
        float4* srow = (float4*)(s_sorted + (size_t)pos * 8);
        srow[0] = make_float4(g0, g1, g2, g3);
        srow[1] = make_float4(g4, g5, g6, g7);
    }

    __syncthreads();   // staging writes -> transpose reads (single wave: waitcnt only)

    // transposed write-out: 16 iterations, each a fully-coalesced 1KB store
    float4* __restrict__ out4 = (float4*)(e_out + (size_t)base * 64);
    const size_t limit4 = (size_t)E * 16;             // e_out size in float4s
    const size_t base4  = (size_t)base * 16;
#pragma unroll
    for (int i = 0; i < 16; ++i) {
        const int f   = i * 64 + lane;                // float4 index within tile
        const int r   = (f >> 4);                     // tile row  = i*4 + lane/16
        const int m   = f & 15;                       // tile col (float4 units)
        const float4 v = tile4[r * 16 + (m ^ (r & 15))];
        if (base4 + (size_t)f < limit4) out4[f] = v;
    }
}

// ---------------- aggregation: one wave per node, no atomics ----------------
__global__ __launch_bounds__(256)
void aggregate_kernel(const int* __restrict__ offsets,
                      const int* __restrict__ src_sorted,
                      const float* __restrict__ s_sorted,
                      const float* __restrict__ V,
                      float* __restrict__ hout, int n)
{
    const int w = (blockIdx.x * 256 + threadIdx.x) >> 6;
    const int lane = threadIdx.x & 63;
    if (w >= n) return;
    const int o0 = offsets[w], o1 = offsets[w + 1];
    const int head = lane >> 3;
    float acc = 0.f, zacc = 0.f;
    int j = o0;
    for (; j + 4 <= o1; j += 4) {
        const int sv0 = src_sorted[j + 0];
        const int sv1 = src_sorted[j + 1];
        const int sv2 = src_sorted[j + 2];
        const int sv3 = src_sorted[j + 3];
        const float s0 = s_sorted[(size_t)(j + 0) * 8 + head];
        const float s1 = s_sorted[(size_t)(j + 1) * 8 + head];
        const float s2 = s_sorted[(size_t)(j + 2) * 8 + head];
        const float s3 = s_sorted[(size_t)(j + 3) * 8 + head];
        const float v0 = V[(size_t)sv0 * 64 + lane];
        const float v1 = V[(size_t)sv1 * 64 + lane];
        const float v2 = V[(size_t)sv2 * 64 + lane];
        const float v3 = V[(size_t)sv3 * 64 + lane];
        acc = fmaf(v0, s0, acc);
        acc = fmaf(v1, s1, acc);
        acc = fmaf(v2, s2, acc);
        acc = fmaf(v3, s3, acc);
        zacc += (s0 + s1) + (s2 + s3);
    }
    for (; j < o1; ++j) {
        const int sv = src_sorted[j];
        const float s = s_sorted[(size_t)j * 8 + head];
        acc = fmaf(V[(size_t)sv * 64 + lane], s, acc);
        zacc += s;
    }
    hout[(size_t)w * 64 + lane] = acc / (zacc + 1e-6f);
}

extern "C" void kernel_launch(void* const* d_in, const int* in_sizes, int n_in,
                              void* d_out, int out_size, void* d_ws, size_t ws_size,
                              hipStream_t stream)
{
    const float* h  = (const float*)d_in[0];
    const float* e  = (const float*)d_in[1];
    const float* Wq = (const float*)d_in[2];
    const float* bq = (const float*)d_in[3];
    const float* Wk = (const float*)d_in[4];
    const float* bk = (const float*)d_in[5];
    const float* Wv = (const float*)d_in[6];
    const float* bv = (const float*)d_in[7];
    const float* We = (const float*)d_in[8];
    const float* be = (const float*)d_in[9];
    const int* src  = (const int*)d_in[10];
    const int* dst  = (const int*)d_in[11];

    const int N = in_sizes[0] / 64;
    const int E = in_sizes[1] / 64;

    float* hout  = (float*)d_out;                    // [N*64]
    float* e_out = (float*)d_out + (size_t)N * 64;   // [E*64]

    // workspace layout
    char* ws = (char*)d_ws;
    float* Q = (float*)ws;                 ws += (size_t)N * 64 * sizeof(float);
    float* K = (float*)ws;                 ws += (size_t)N * 64 * sizeof(float);
    float* V = (float*)ws;                 ws += (size_t)N * 64 * sizeof(float);
    float* s_sorted = (float*)ws;          ws += (size_t)E * 8 * sizeof(float);
    int* src_sorted = (int*)ws;            ws += (size_t)E * sizeof(int);
    int* counts  = (int*)ws;               ws += (size_t)N * sizeof(int);
    int* offsets = (int*)ws;               ws += (size_t)(N + 1) * sizeof(int);
    int* cursor  = (int*)ws;               ws += (size_t)N * sizeof(int);

    hipMemsetAsync(counts, 0, (size_t)N * sizeof(int), stream);

    // 1) Q,K,V projections
    proj_kernel<<<dim3(512, 3), dim3(256), 0, stream>>>(
        h, Wq, bq, Wk, bk, Wv, bv, Q, K, V, N);

    // 2) dst histogram
    hist_kernel<<<dim3(2048), dim3(256), 0, stream>>>(dst, counts, E);

    // 3) exclusive scan -> offsets, cursor
    scan_kernel<<<dim3(1), dim3(1024), 0, stream>>>(counts, offsets, cursor, N, E);

    // 4) edge pass: one wave per 64-edge tile, LDS-transposed e_out
    const int ntiles = (E + 63) >> 6;               // 25000 wave-tiles
    edge_kernel<<<dim3(ntiles), dim3(64), 0, stream>>>(
        e, We, be, src, dst, Q, K, e_out, s_sorted, src_sorted, cursor, E);

    // 5) aggregate per node (one wave each)
    const int ablocks = (N * 64 + 255) / 256;
    aggregate_kernel<<<dim3(ablocks), dim3(256), 0, stream>>>(
        offsets, src_sorted, s_sorted, V, hout, N);
}